// Round 10
// baseline (127.240 us; speedup 1.0000x reference)
//
#include <hip/hip_runtime.h>
#include <hip/hip_bf16.h>
#include <cmath>

#define KS 84   // row stride in ushorts (bank-decorrelated, 8B-aligned rows)

// ---- packed-weight layout in d_ws (float offsets) ----
#define OFF_W1    0      // 64 x float4 {W1[0][j],W1[1][j],W1[2][j],b1[j]}
#define OFF_W1E   256    // 64 x float4 {h|W1x|, h|W1y|, h|W1z|, W2[j][0]}  h=0.005
#define OFF_W1S   512    // 64 x float4 {W2j*sgn(W1x), W2j*sgn(W1y), W2j*sgn(W1z), 0}
#define OFF_WC2   768    // 64 x float4 {Wc2[c][0..2], 0}
#define OFF_BC2   1024   // {bc2[0],bc2[1],bc2[2], b2[0]}
#define OFF_GC    1028   // {sum_j Sx*Hx, sum_j Sy*Hy, sum_j Sz*Hz}  (const half of FD grad)
#define OFF_AF    1032   // 10 frags x 64 lanes x 8 bf16, A-operand-swizzled (16B/lane/frag)

typedef __attribute__((ext_vector_type(4))) short  short4v;
typedef __attribute__((ext_vector_type(8))) short  short8v;
typedef __attribute__((ext_vector_type(16))) float f32x16;

__device__ __forceinline__ float sigm(float x){ return 1.0f/(1.0f + expf(-x)); }
__device__ __forceinline__ float clampf(float x, float lo, float hi){ return fminf(fmaxf(x, lo), hi); }
__device__ __forceinline__ unsigned short f2bf(float x){
  __hip_bfloat16 h = __float2bfloat16(x);
  return *reinterpret_cast<unsigned short*>(&h);
}
// HW packed bf16 convert (RTNE, same rounding as __float2bfloat16):
__device__ __forceinline__ unsigned cvt_pk_bf16(float a, float b){
  unsigned r;
  asm("v_cvt_pk_bf16_f32 %0, %1, %2" : "=v"(r) : "v"(a), "v"(b));
  return r;
}
__device__ __forceinline__ short8v lds_load8(const unsigned short* p){
  short4v lo = *(const short4v*)p;
  short4v hi = *(const short4v*)(p + 4);
  short8v r;
  r[0]=lo[0]; r[1]=lo[1]; r[2]=lo[2]; r[3]=lo[3];
  r[4]=hi[0]; r[5]=hi[1]; r[6]=hi[2]; r[7]=hi[3];
  return r;
}

// Prep (1 block, 256 threads), load-then-compute (unchanged from round 5).
__global__ __launch_bounds__(256)
void prep_weights(const float* __restrict__ W1, const float* __restrict__ b1,
                  const float* __restrict__ W2, const float* __restrict__ b2,
                  const float* __restrict__ Wc1, const float* __restrict__ bc1,
                  const float* __restrict__ Wc2, const float* __restrict__ bc2,
                  float* __restrict__ ws)
{
  __shared__ float LW2[4160];    // (64 x 65)
  __shared__ float LWc1[4672];   // (73 x 64)
  __shared__ float LW1[192];
  __shared__ float Lb1[64];
  __shared__ float Lb2[65];
  __shared__ float Lbc1[64];
  __shared__ float LWc2[192];
  __shared__ float Lbc2[3];
  __shared__ float s_cb[4][64];
  __shared__ unsigned short W2T[64*KS];   // [k][t] = W2[k][1+t] bf16
  __shared__ unsigned short ABUF[64*KS];  // A[c][k] bf16
  const int tid  = threadIdx.x;
  const int lane = tid & 63;
  const int wv   = tid >> 6;
  const int l31  = lane & 31;
  const int h    = lane >> 5;

  // ---- phase 0: coalesced staging ----
  {
    const float4* s4 = (const float4*)W2;
    float4* d4 = (float4*)LW2;
    for (int i = tid; i < 1040; i += 256) d4[i] = s4[i];
    const float4* c4 = (const float4*)Wc1;
    float4* e4 = (float4*)LWc1;
    for (int i = tid; i < 1168; i += 256) e4[i] = c4[i];
  }
  if (tid < 192) LW1[tid]  = W1[tid];
  if (tid < 64)  Lb1[tid]  = b1[tid];
  if (tid < 65)  Lb2[tid]  = b2[tid];
  if (tid < 64)  Lbc1[tid] = bc1[tid];
  if (tid < 192) LWc2[tid] = Wc2[tid];
  if (tid < 3)   Lbc2[tid] = bc2[tid];
  __syncthreads();

  // ---- phase 1 (LDS -> LDS/ws) ----
  for (int i = tid; i < 4096; i += 256){
    int k = i >> 6, t = i & 63;
    W2T[k*KS + t] = f2bf(LW2[k*65 + 1 + t]);
  }
  for (int i = tid; i < 576; i += 256){
    int ii = i >> 6, c = i & 63;
    ABUF[c*KS + 64 + ii] = f2bf(LWc1[ii*64 + c]);
  }
  for (int i = tid; i < 384; i += 256){
    int z = i >> 6, c = i & 63;
    ABUF[c*KS + 74 + z] = 0;
  }
  // cb row partials: thread (q=tid>>6, c=tid&63) sums t in [16q, 16q+16)
  {
    int c = tid & 63, q = tid >> 6;
    float acc = 0.f;
    #pragma unroll
    for (int t = 16*q; t < 16*q + 16; ++t)
      acc = fmaf(Lb2[1+t], LWc1[(9+t)*64 + c], acc);
    s_cb[q][c] = acc;
  }
  // small packs (all of wave 0 -> shfl reduce for gc is wave-uniform)
  if (tid < 64){
    int j = tid;
    float wx = LW1[j], wy = LW1[64+j], wz = LW1[128+j];
    float w2 = LW2[j*65];
    float Hx = 0.005f * fabsf(wx);
    float Hy = 0.005f * fabsf(wy);
    float Hz = 0.005f * fabsf(wz);
    float Sx = (wx < 0.f) ? -w2 : w2;
    float Sy = (wy < 0.f) ? -w2 : w2;
    float Sz = (wz < 0.f) ? -w2 : w2;
    ws[OFF_W1 + 4*j + 0] = wx;
    ws[OFF_W1 + 4*j + 1] = wy;
    ws[OFF_W1 + 4*j + 2] = wz;
    ws[OFF_W1 + 4*j + 3] = Lb1[j];
    ws[OFF_W1E + 4*j + 0] = Hx;
    ws[OFF_W1E + 4*j + 1] = Hy;
    ws[OFF_W1E + 4*j + 2] = Hz;
    ws[OFF_W1E + 4*j + 3] = w2;
    ws[OFF_W1S + 4*j + 0] = Sx;
    ws[OFF_W1S + 4*j + 1] = Sy;
    ws[OFF_W1S + 4*j + 2] = Sz;
    ws[OFF_W1S + 4*j + 3] = 0.f;
    float sx = Sx*Hx, sy = Sy*Hy, sz = Sz*Hz;
    #pragma unroll
    for (int off = 1; off < 64; off <<= 1){
      sx += __shfl_xor(sx, off);
      sy += __shfl_xor(sy, off);
      sz += __shfl_xor(sz, off);
    }
    if (j == 0){
      ws[OFF_GC + 0] = sx;
      ws[OFF_GC + 1] = sy;
      ws[OFF_GC + 2] = sz;
    }
  } else if (tid < 128){
    int j = tid - 64;
    ws[OFF_WC2 + 4*j + 0] = LWc2[j*3+0];
    ws[OFF_WC2 + 4*j + 1] = LWc2[j*3+1];
    ws[OFF_WC2 + 4*j + 2] = LWc2[j*3+2];
    ws[OFF_WC2 + 4*j + 3] = 0.f;
  } else if (tid < 132){
    int j = tid - 128;
    ws[OFF_BC2 + j] = (j < 3) ? Lbc2[j] : Lb2[0];
  }
  __syncthreads();

  // ---- phase 2: cb finalize + per-wave E-tile MFMA ----
  if (tid < 64){
    float acc = Lbc1[tid] + ((s_cb[0][tid] + s_cb[1][tid]) + (s_cb[2][tid] + s_cb[3][tid]));
    ABUF[tid*KS + 73] = f2bf(acc);
  }
  {
    const int mb = wv & 1, kb = wv >> 1;
    f32x16 e;
    #pragma unroll
    for (int i = 0; i < 16; ++i) e[i] = 0.f;
    #pragma unroll
    for (int s = 0; s < 4; ++s){
      short8v afr;
      #pragma unroll
      for (int j = 0; j < 8; ++j)
        afr[j] = (short)f2bf(LWc1[(9 + 16*s + 8*h + j)*64 + 32*mb + l31]);
      short8v bfr = lds_load8(&W2T[(32*kb + l31)*KS + 16*s + 8*h]);
      e = __builtin_amdgcn_mfma_f32_32x32x16_bf16(afr, bfr, e, 0, 0, 0);
    }
    const int kcol = 32*kb + l31;
    #pragma unroll
    for (int r = 0; r < 16; ++r){
      int c = 32*mb + (r & 3) + 8*(r >> 2) + 4*h;
      ABUF[c*KS + kcol] = f2bf(e[r]);
    }
  }
  __syncthreads();

  // ---- phase 3: extract pre-swizzled A-fragments -> ws ----
  for (int i = tid; i < 640; i += 256){
    int f = i >> 6, ln = i & 63;
    int mb = f / 5, kk = f - 5*mb;
    int c  = 32*mb + (ln & 31);
    int kb2 = 16*kk + 8*(ln >> 5);
    short8v v = lds_load8(&ABUF[c*KS + kb2]);
    *((short8v*)(((unsigned short*)(ws + OFF_AF)) + (size_t)i * 8)) = v;
  }
}

// One block = ONE WAVE, processing rays in a grid-stride loop (2 rays/block
// at grid=2048): persistent blocks keep every CU's residency pinned for the
// whole kernel (ramp/tail amortized), and block-invariant state (s_wc2, the
// 40-VGPR af fragments) is paid once per block instead of once per ray.
// Per-ray body identical to round 8 (best measured: 44.0 us).
__global__ __launch_bounds__(64, 8)
void neus_render(const float* __restrict__ rays_o, const float* __restrict__ rays_d,
                 const float* __restrict__ inv_s_p, const float* __restrict__ ws,
                 float* __restrict__ out, int nrays)
{
  __shared__ unsigned short s_aext[64*KS];   // activation rows (bf16), reused per batch
  __shared__ float4 s_wc2[64];
  __shared__ float  s_z[64];
  __shared__ float  s_cdf[64];
  __shared__ float  s_newz[64];
  __shared__ float  s_zall[128];

  const int lane = threadIdx.x;

  const float4* __restrict__ pW1  = (const float4*)(ws + OFF_W1);
  const float4* __restrict__ pW1E = (const float4*)(ws + OFF_W1E);
  const float4* __restrict__ pW1S = (const float4*)(ws + OFF_W1S);
  const float*  __restrict__ pbc2 = ws + OFF_BC2;
  const float*  __restrict__ pgc  = ws + OFF_GC;
  const float b20 = pbc2[3];

  s_wc2[lane] = ((const float4*)(ws + OFF_WC2))[lane];
  const float inv_s = expf(10.f * inv_s_p[0]);
  const float gc0 = pgc[0], gc1 = pgc[1], gc2 = pgc[2];

  // A-fragments (weights, pre-swizzled bf16) — block-invariant, loaded once
  const short8v* pAF = (const short8v*)(ws + OFF_AF);
  short8v af[10];
  #pragma unroll
  for (int f = 0; f < 10; ++f) af[f] = pAF[f*64 + lane];

  const int scol = lane & 31;
  const int half8 = (lane >> 5) * 8;
  const int halfoff = (lane >> 5) * 4;
  const bool hihalf = (lane >= 32);
  unsigned short* arow = &s_aext[(unsigned)lane * KS];
  const unsigned short* aw = s_aext;

  for (int ray = blockIdx.x; ray < nrays; ray += gridDim.x){

    // ---- per-ray setup ----
    float ox = rays_o[ray*3], oy = rays_o[ray*3+1], oz = rays_o[ray*3+2];
    float dx = rays_d[ray*3], dy = rays_d[ray*3+1], dz = rays_d[ray*3+2];
    float tnx = (-1.f-ox)/(dx+1e-15f), tfx = (1.f-ox)/(dx+1e-15f);
    float tny = (-1.f-oy)/(dy+1e-15f), tfy = (1.f-oy)/(dy+1e-15f);
    float tnz = (-1.f-oz)/(dz+1e-15f), tfz = (1.f-oz)/(dz+1e-15f);
    float nearv = fmaxf(fmaxf(fminf(tnx,tfx), fminf(tny,tfy)), fminf(tnz,tfz));
    float farv  = fminf(fminf(fmaxf(tnx,tfx), fmaxf(tny,tfy)), fmaxf(tnz,tfz));
    nearv = fmaxf(nearv, 0.05f);
    const float sd = (farv - nearv) * (1.f/64.f);

    // ---- coarse pass (lane = coarse sample) ----
    {
      float zt = nearv + (farv-nearv) * ((float)lane * (1.f/63.f));
      float px = clampf(ox + dx*zt, -1.f, 1.f);
      float py = clampf(oy + dy*zt, -1.f, 1.f);
      float pz = clampf(oz + dz*zt, -1.f, 1.f);
      float acc0 = b20, acc1 = 0.f;   // 2 chains: halve the serial fma depth
      #pragma unroll 4
      for (int q = 0; q < 32; ++q){
        int j = 2*q;
        float4 wa = pW1[j];
        float4 wb = pW1[j+1];
        float ea = pW1E[j].w;
        float eb = pW1E[j+1].w;
        float ha = fmaxf(fmaf(px, wa.x, fmaf(py, wa.y, fmaf(pz, wa.z, wa.w))), 0.f);
        float hb = fmaxf(fmaf(px, wb.x, fmaf(py, wb.y, fmaf(pz, wb.z, wb.w))), 0.f);
        acc0 = fmaf(ha, ea, acc0);
        acc1 = fmaf(hb, eb, acc1);
      }
      float acc = acc0 + acc1;
      s_z[lane] = zt;
      float s1  = __shfl_down(acc, 1);
      float zt1 = nearv + (farv-nearv) * ((float)(lane+1) * (1.f/63.f));
      float a_c = 0.f, qv = 1.f;
      if (lane < 63){
        float dc   = zt1 - zt;
        float mid  = 0.5f*(acc + s1);
        float cosv = clampf((s1-acc)/(dc+1e-5f), -1000.f, 0.f);
        float est  = cosv*dc*0.5f;
        float pcv  = sigm((mid-est)*64.f);
        float ncv  = sigm((mid+est)*64.f);
        a_c = clampf((pcv-ncv+1e-5f)/(pcv+1e-5f), 0.f, 1.f);
        qv  = 1.f - a_c + 1e-7f;
      }
      float p = qv;
      #pragma unroll
      for (int off = 1; off < 64; off <<= 1){
        float t = __shfl_up(p, off);
        if (lane >= off) p *= t;
      }
      float ec = __shfl_up(p, 1);
      if (lane == 0) ec = 1.f;
      float wvv = (lane < 63) ? (a_c*ec + 1e-5f) : 0.f;
      float tot = wvv;
      #pragma unroll
      for (int off = 32; off > 0; off >>= 1) tot += __shfl_xor(tot, off);
      float cs = wvv;
      #pragma unroll
      for (int off = 1; off < 64; off <<= 1){
        float t = __shfl_up(cs, off);
        if (lane >= off) cs += t;
      }
      if (lane == 0)  s_cdf[0] = 0.f;
      if (lane < 63)  s_cdf[lane+1] = cs / tot;
    }
    __syncthreads();   // 1-wave barrier: memory ordering only

    // ---- sample_pdf (searchsorted right + lerp) ----
    {
      float u = ((float)lane + 0.5f) * (1.f/64.f);
      int lo = 0, hi = 64;
      while (lo < hi){
        int m = (lo+hi) >> 1;
        if (s_cdf[m] <= u) lo = m+1; else hi = m;
      }
      int below = lo - 1;
      int above = lo < 63 ? lo : 63;
      float cb = s_cdf[below], ca = s_cdf[above];
      float bb = s_z[below],   ba = s_z[above];
      float den = ca - cb; if (den < 1e-5f) den = 1.f;
      float tt = (u - cb)/den;
      s_newz[lane] = bb + tt*(ba - bb);
    }
    __syncthreads();

    // ---- parallel merge of two sorted 64-lists (each lane places 2 elems) ----
    {
      float v0 = s_z[lane];
      int lo0 = 0, hi0 = 64;
      while (lo0 < hi0){ int m=(lo0+hi0)>>1; if (s_newz[m] < v0) lo0 = m+1; else hi0 = m; }
      float v1 = s_newz[lane];
      int lo1 = 0, hi1 = 64;
      while (lo1 < hi1){ int m=(lo1+hi1)>>1; if (s_z[m] <= v1) lo1 = m+1; else hi1 = m; }
      s_zall[lane + lo0] = v0;
      s_zall[lane + lo1] = v1;
    }
    __syncthreads();

    // ---- fine pass: 2 batches of 64 samples, one wave, shared aext buffer ----
    float rA = 0.f, rB = 0.f, rC = 0.f, rD = 0.f;   // composite accumulators
    float Tc = 1.f;                                  // carried transmittance

    for (int b = 0; b < 2; ++b){
      const int lt2 = 64*b + lane;
      float zc = s_zall[lt2];
      float zn = s_zall[lt2 < 127 ? lt2+1 : 127];
      float delta = (lt2 < 127) ? (zn - zc) : sd;
      float zm    = (lt2 < 127) ? (zc + 0.5f*delta) : zc;
      float px = clampf(ox + dx*zm, -1.f, 1.f);
      float py = clampf(oy + dy*zm, -1.f, 1.f);
      float pz = clampf(oz + dz*zm, -1.f, 1.f);

      // layer-1 + sdf col-0 + FD grad via exact identity:
      //   relu(b+hw)-relu(b-hw) = sgn(w)*(med3(b,-h|w|,h|w|) + h|w|)
      float sa0 = b20, sa1 = 0.f;
      float gxa = gc0, gya = gc1, gza = gc2;
      float gxb = 0.f, gyb = 0.f, gzb = 0.f;
      #pragma unroll 2
      for (int q = 0; q < 16; ++q){
        int j = 4*q;
        float4 w0 = pW1[j],   e0 = pW1E[j],   s0 = pW1S[j];
        float4 w1 = pW1[j+1], e1 = pW1E[j+1], s1v = pW1S[j+1];
        float4 w2 = pW1[j+2], e2 = pW1E[j+2], s2v = pW1S[j+2];
        float4 w3 = pW1[j+3], e3 = pW1E[j+3], s3v = pW1S[j+3];
        float base0 = fmaf(px, w0.x, fmaf(py, w0.y, fmaf(pz, w0.z, w0.w)));
        float base1 = fmaf(px, w1.x, fmaf(py, w1.y, fmaf(pz, w1.z, w1.w)));
        float base2 = fmaf(px, w2.x, fmaf(py, w2.y, fmaf(pz, w2.z, w2.w)));
        float base3 = fmaf(px, w3.x, fmaf(py, w3.y, fmaf(pz, w3.z, w3.w)));
        float hv0 = fmaxf(base0, 0.f), hv1 = fmaxf(base1, 0.f);
        float hv2 = fmaxf(base2, 0.f), hv3 = fmaxf(base3, 0.f);
        sa0 = fmaf(hv0, e0.w, sa0); sa0 = fmaf(hv1, e1.w, sa0);
        sa1 = fmaf(hv2, e2.w, sa1); sa1 = fmaf(hv3, e3.w, sa1);
        gxa = fmaf(__builtin_amdgcn_fmed3f(base0, -e0.x, e0.x), s0.x, gxa);
        gya = fmaf(__builtin_amdgcn_fmed3f(base0, -e0.y, e0.y), s0.y, gya);
        gza = fmaf(__builtin_amdgcn_fmed3f(base0, -e0.z, e0.z), s0.z, gza);
        gxa = fmaf(__builtin_amdgcn_fmed3f(base1, -e1.x, e1.x), s1v.x, gxa);
        gya = fmaf(__builtin_amdgcn_fmed3f(base1, -e1.y, e1.y), s1v.y, gya);
        gza = fmaf(__builtin_amdgcn_fmed3f(base1, -e1.z, e1.z), s1v.z, gza);
        gxb = fmaf(__builtin_amdgcn_fmed3f(base2, -e2.x, e2.x), s2v.x, gxb);
        gyb = fmaf(__builtin_amdgcn_fmed3f(base2, -e2.y, e2.y), s2v.y, gyb);
        gzb = fmaf(__builtin_amdgcn_fmed3f(base2, -e2.z, e2.z), s2v.z, gzb);
        gxb = fmaf(__builtin_amdgcn_fmed3f(base3, -e3.x, e3.x), s3v.x, gxb);
        gyb = fmaf(__builtin_amdgcn_fmed3f(base3, -e3.y, e3.y), s3v.y, gyb);
        gzb = fmaf(__builtin_amdgcn_fmed3f(base3, -e3.z, e3.z), s3v.z, gzb);
        *(unsigned*)&arow[j]   = cvt_pk_bf16(hv0, hv1);
        *(unsigned*)&arow[j+2] = cvt_pk_bf16(hv2, hv3);
      }
      float sdfv = sa0 + sa1;
      float gx = (gxa+gxb)*100.f, gy = (gya+gyb)*100.f, gz = (gza+gzb)*100.f;
      float gn = 1e-5f + sqrtf(gx*gx + gy*gy + gz*gz);
      float nx = gx/gn, ny = gy/gn, nz = gz/gn;

      // ext slots: k=64..72 = [pt,dir,n], k=73 = 1, k=74..79 = 0
      *(unsigned*)&arow[64] = cvt_pk_bf16(px, py);
      *(unsigned*)&arow[66] = cvt_pk_bf16(pz, dx);
      *(unsigned*)&arow[68] = cvt_pk_bf16(dy, dz);
      *(unsigned*)&arow[70] = cvt_pk_bf16(nx, ny);
      *(unsigned*)&arow[72] = cvt_pk_bf16(nz, 1.0f);
      *(unsigned*)&arow[74] = 0u;
      *(unsigned*)&arow[76] = 0u;
      *(unsigned*)&arow[78] = 0u;

      // ---- NeuS alpha + transmittance scan (register-carried across batches) ----
      float tcos = dx*nx + dy*ny + dz*nz;
      float aarg = -100.f * tcos;
      float spv  = (aarg > 0.f) ? (aarg + log1pf(expf(-aarg))) : log1pf(expf(aarg));
      float iter_cos = -(spv * 0.01f);
      float est = iter_cos * delta * 0.5f;
      float pcv = sigm((sdfv - est)*inv_s);
      float ncv = sigm((sdfv + est)*inv_s);
      float alpha = clampf((pcv - ncv + 1e-5f)/(pcv + 1e-5f), 0.f, 1.f);

      float qv = 1.f - alpha + 1e-7f;
      float p = qv;
      #pragma unroll
      for (int off = 1; off < 64; off <<= 1){
        float t = __shfl_up(p, off);
        if (lane >= off) p *= t;
      }
      float excl = __shfl_up(p, 1);
      if (lane == 0) excl = 1.f;
      excl *= Tc;
      float w = alpha * excl;
      Tc *= __shfl(p, 63);

      __syncthreads();   // trivial: fences aext LDS writes before MFMA reads

      // MFMA: C[c][s] = A(64x80) x aext^T(80x64)
      f32x16 acc00, acc01, acc10, acc11;
      #pragma unroll
      for (int i = 0; i < 16; ++i){ acc00[i]=0.f; acc01[i]=0.f; acc10[i]=0.f; acc11[i]=0.f; }
      #pragma unroll
      for (int kk = 0; kk < 5; ++kk){
        int koff = 16*kk + half8;
        short8v b0 = lds_load8(&aw[ scol      * KS + koff]);
        short8v b1 = lds_load8(&aw[(32+scol) * KS + koff]);
        acc00 = __builtin_amdgcn_mfma_f32_32x32x16_bf16(af[kk],   b0, acc00, 0, 0, 0);
        acc10 = __builtin_amdgcn_mfma_f32_32x32x16_bf16(af[5+kk], b0, acc10, 0, 0, 0);
        acc01 = __builtin_amdgcn_mfma_f32_32x32x16_bf16(af[kk],   b1, acc01, 0, 0, 0);
        acc11 = __builtin_amdgcn_mfma_f32_32x32x16_bf16(af[5+kk], b1, acc11, 0, 0, 0);
      }

      // relu -> *Wc2 -> reduce over c: in-lane over regs, cross-half via shfl_xor(32)
      float pr0=0.f,pr1=0.f,pr2=0.f,pr3=0.f,pr4=0.f,pr5=0.f;
      #pragma unroll
      for (int r = 0; r < 16; ++r){
        int ci = (r & 3) + 8*(r >> 2) + halfoff;
        float4 wA = s_wc2[ci];
        float4 wB = s_wc2[32 + ci];
        float v;
        v = fmaxf(acc00[r], 0.f); pr0 = fmaf(v, wA.x, pr0); pr1 = fmaf(v, wA.y, pr1); pr2 = fmaf(v, wA.z, pr2);
        v = fmaxf(acc10[r], 0.f); pr0 = fmaf(v, wB.x, pr0); pr1 = fmaf(v, wB.y, pr1); pr2 = fmaf(v, wB.z, pr2);
        v = fmaxf(acc01[r], 0.f); pr3 = fmaf(v, wA.x, pr3); pr4 = fmaf(v, wA.y, pr4); pr5 = fmaf(v, wA.z, pr5);
        v = fmaxf(acc11[r], 0.f); pr3 = fmaf(v, wB.x, pr3); pr4 = fmaf(v, wB.y, pr4); pr5 = fmaf(v, wB.z, pr5);
      }
      pr0 += __shfl_xor(pr0, 32); pr1 += __shfl_xor(pr1, 32); pr2 += __shfl_xor(pr2, 32);
      pr3 += __shfl_xor(pr3, 32); pr4 += __shfl_xor(pr4, 32); pr5 += __shfl_xor(pr5, 32);
      float c0 = sigm((hihalf ? pr3 : pr0) + pbc2[0]);
      float c1 = sigm((hihalf ? pr4 : pr1) + pbc2[1]);
      float c2 = sigm((hihalf ? pr5 : pr2) + pbc2[2]);

      rA += w; rB += w*c0; rC += w*c1; rD += w*c2;

      __syncthreads();   // trivial: MFMA reads done before next batch overwrites aext
    }

    // ---- composite (single cross-lane reduce over both batches) ----
    #pragma unroll
    for (int off = 32; off > 0; off >>= 1){
      rA += __shfl_xor(rA, off);
      rB += __shfl_xor(rB, off);
      rC += __shfl_xor(rC, off);
      rD += __shfl_xor(rD, off);
    }
    if (lane == 0){
      float bg = 1.f - rA;
      out[ray*3+0] = rB + bg;
      out[ray*3+1] = rC + bg;
      out[ray*3+2] = rD + bg;
    }
    __syncthreads();   // LDS quiesced before next ray reuses buffers
  }
}

extern "C" void kernel_launch(void* const* d_in, const int* in_sizes, int n_in,
                              void* d_out, int out_size, void* d_ws, size_t ws_size,
                              hipStream_t stream)
{
  const float* rays_o = (const float*)d_in[0];
  const float* rays_d = (const float*)d_in[1];
  const float* W1  = (const float*)d_in[2];
  const float* b1  = (const float*)d_in[3];
  const float* W2  = (const float*)d_in[4];
  const float* b2  = (const float*)d_in[5];
  const float* Wc1 = (const float*)d_in[6];
  const float* bc1 = (const float*)d_in[7];
  const float* Wc2 = (const float*)d_in[8];
  const float* bc2 = (const float*)d_in[9];
  const float* inv_s = (const float*)d_in[10];
  float* out = (float*)d_out;
  float* ws  = (float*)d_ws;

  prep_weights<<<1, 256, 0, stream>>>(W1, b1, W2, b2, Wc1, bc1, Wc2, bc2, ws);

  const int R = in_sizes[0] / 3;               // 4096 rays
  int blocks = R / 2;                          // persistent: 2 rays per block
  if (blocks > R) blocks = R;
  neus_render<<<dim3(blocks), dim3(64), 0, stream>>>(rays_o, rays_d, inv_s, ws, out, R);
}

// Round 11
// 124.370 us; speedup vs baseline: 1.0231x; 1.0231x over previous
//
#include <hip/hip_runtime.h>
#include <hip/hip_bf16.h>
#include <cmath>

#define KS 84   // row stride in ushorts (bank-decorrelated, 8B-aligned rows)

// ---- packed-weight layout in d_ws (float offsets) ----
#define OFF_W1    0      // 64 x float4 {W1[0][j],W1[1][j],W1[2][j],b1[j]}
#define OFF_W1E   256    // 64 x float4 {h|W1x|, h|W1y|, h|W1z|, W2[j][0]}  h=0.005
#define OFF_W1S   512    // 64 x float4 {W2j*sgn(W1x), W2j*sgn(W1y), W2j*sgn(W1z), 0}
#define OFF_WC2   768    // 64 x float4 {Wc2[c][0..2], 0}
#define OFF_BC2   1024   // {bc2[0],bc2[1],bc2[2], b2[0]}
#define OFF_GC    1028   // {sum_j Sx*Hx, sum_j Sy*Hy, sum_j Sz*Hz}  (const half of FD grad)
#define OFF_AF    1032   // 10 frags x 64 lanes x 8 bf16, A-operand-swizzled (16B/lane/frag)

typedef __attribute__((ext_vector_type(4))) short  short4v;
typedef __attribute__((ext_vector_type(8))) short  short8v;
typedef __attribute__((ext_vector_type(16))) float f32x16;

__device__ __forceinline__ float sigm(float x){ return 1.0f/(1.0f + expf(-x)); }
__device__ __forceinline__ float clampf(float x, float lo, float hi){ return fminf(fmaxf(x, lo), hi); }
__device__ __forceinline__ unsigned short f2bf(float x){
  __hip_bfloat16 h = __float2bfloat16(x);
  return *reinterpret_cast<unsigned short*>(&h);
}
// HW packed bf16 convert (RTNE, same rounding as __float2bfloat16):
__device__ __forceinline__ unsigned cvt_pk_bf16(float a, float b){
  unsigned r;
  asm("v_cvt_pk_bf16_f32 %0, %1, %2" : "=v"(r) : "v"(a), "v"(b));
  return r;
}
__device__ __forceinline__ short8v lds_load8(const unsigned short* p){
  short4v lo = *(const short4v*)p;
  short4v hi = *(const short4v*)(p + 4);
  short8v r;
  r[0]=lo[0]; r[1]=lo[1]; r[2]=lo[2]; r[3]=lo[3];
  r[4]=hi[0]; r[5]=hi[1]; r[6]=hi[2]; r[7]=hi[3];
  return r;
}

// Prep (1 block, 256 threads), load-then-compute (unchanged from round 5).
__global__ __launch_bounds__(256)
void prep_weights(const float* __restrict__ W1, const float* __restrict__ b1,
                  const float* __restrict__ W2, const float* __restrict__ b2,
                  const float* __restrict__ Wc1, const float* __restrict__ bc1,
                  const float* __restrict__ Wc2, const float* __restrict__ bc2,
                  float* __restrict__ ws)
{
  __shared__ float LW2[4160];    // (64 x 65)
  __shared__ float LWc1[4672];   // (73 x 64)
  __shared__ float LW1[192];
  __shared__ float Lb1[64];
  __shared__ float Lb2[65];
  __shared__ float Lbc1[64];
  __shared__ float LWc2[192];
  __shared__ float Lbc2[3];
  __shared__ float s_cb[4][64];
  __shared__ unsigned short W2T[64*KS];   // [k][t] = W2[k][1+t] bf16
  __shared__ unsigned short ABUF[64*KS];  // A[c][k] bf16
  const int tid  = threadIdx.x;
  const int lane = tid & 63;
  const int wv   = tid >> 6;
  const int l31  = lane & 31;
  const int h    = lane >> 5;

  // ---- phase 0: coalesced staging ----
  {
    const float4* s4 = (const float4*)W2;
    float4* d4 = (float4*)LW2;
    for (int i = tid; i < 1040; i += 256) d4[i] = s4[i];
    const float4* c4 = (const float4*)Wc1;
    float4* e4 = (float4*)LWc1;
    for (int i = tid; i < 1168; i += 256) e4[i] = c4[i];
  }
  if (tid < 192) LW1[tid]  = W1[tid];
  if (tid < 64)  Lb1[tid]  = b1[tid];
  if (tid < 65)  Lb2[tid]  = b2[tid];
  if (tid < 64)  Lbc1[tid] = bc1[tid];
  if (tid < 192) LWc2[tid] = Wc2[tid];
  if (tid < 3)   Lbc2[tid] = bc2[tid];
  __syncthreads();

  // ---- phase 1 (LDS -> LDS/ws) ----
  for (int i = tid; i < 4096; i += 256){
    int k = i >> 6, t = i & 63;
    W2T[k*KS + t] = f2bf(LW2[k*65 + 1 + t]);
  }
  for (int i = tid; i < 576; i += 256){
    int ii = i >> 6, c = i & 63;
    ABUF[c*KS + 64 + ii] = f2bf(LWc1[ii*64 + c]);
  }
  for (int i = tid; i < 384; i += 256){
    int z = i >> 6, c = i & 63;
    ABUF[c*KS + 74 + z] = 0;
  }
  // cb row partials: thread (q=tid>>6, c=tid&63) sums t in [16q, 16q+16)
  {
    int c = tid & 63, q = tid >> 6;
    float acc = 0.f;
    #pragma unroll
    for (int t = 16*q; t < 16*q + 16; ++t)
      acc = fmaf(Lb2[1+t], LWc1[(9+t)*64 + c], acc);
    s_cb[q][c] = acc;
  }
  // small packs (all of wave 0 -> shfl reduce for gc is wave-uniform)
  if (tid < 64){
    int j = tid;
    float wx = LW1[j], wy = LW1[64+j], wz = LW1[128+j];
    float w2 = LW2[j*65];
    float Hx = 0.005f * fabsf(wx);
    float Hy = 0.005f * fabsf(wy);
    float Hz = 0.005f * fabsf(wz);
    float Sx = (wx < 0.f) ? -w2 : w2;
    float Sy = (wy < 0.f) ? -w2 : w2;
    float Sz = (wz < 0.f) ? -w2 : w2;
    ws[OFF_W1 + 4*j + 0] = wx;
    ws[OFF_W1 + 4*j + 1] = wy;
    ws[OFF_W1 + 4*j + 2] = wz;
    ws[OFF_W1 + 4*j + 3] = Lb1[j];
    ws[OFF_W1E + 4*j + 0] = Hx;
    ws[OFF_W1E + 4*j + 1] = Hy;
    ws[OFF_W1E + 4*j + 2] = Hz;
    ws[OFF_W1E + 4*j + 3] = w2;
    ws[OFF_W1S + 4*j + 0] = Sx;
    ws[OFF_W1S + 4*j + 1] = Sy;
    ws[OFF_W1S + 4*j + 2] = Sz;
    ws[OFF_W1S + 4*j + 3] = 0.f;
    float sx = Sx*Hx, sy = Sy*Hy, sz = Sz*Hz;
    #pragma unroll
    for (int off = 1; off < 64; off <<= 1){
      sx += __shfl_xor(sx, off);
      sy += __shfl_xor(sy, off);
      sz += __shfl_xor(sz, off);
    }
    if (j == 0){
      ws[OFF_GC + 0] = sx;
      ws[OFF_GC + 1] = sy;
      ws[OFF_GC + 2] = sz;
    }
  } else if (tid < 128){
    int j = tid - 64;
    ws[OFF_WC2 + 4*j + 0] = LWc2[j*3+0];
    ws[OFF_WC2 + 4*j + 1] = LWc2[j*3+1];
    ws[OFF_WC2 + 4*j + 2] = LWc2[j*3+2];
    ws[OFF_WC2 + 4*j + 3] = 0.f;
  } else if (tid < 132){
    int j = tid - 128;
    ws[OFF_BC2 + j] = (j < 3) ? Lbc2[j] : Lb2[0];
  }
  __syncthreads();

  // ---- phase 2: cb finalize + per-wave E-tile MFMA ----
  if (tid < 64){
    float acc = Lbc1[tid] + ((s_cb[0][tid] + s_cb[1][tid]) + (s_cb[2][tid] + s_cb[3][tid]));
    ABUF[tid*KS + 73] = f2bf(acc);
  }
  {
    const int mb = wv & 1, kb = wv >> 1;
    f32x16 e;
    #pragma unroll
    for (int i = 0; i < 16; ++i) e[i] = 0.f;
    #pragma unroll
    for (int s = 0; s < 4; ++s){
      short8v afr;
      #pragma unroll
      for (int j = 0; j < 8; ++j)
        afr[j] = (short)f2bf(LWc1[(9 + 16*s + 8*h + j)*64 + 32*mb + l31]);
      short8v bfr = lds_load8(&W2T[(32*kb + l31)*KS + 16*s + 8*h]);
      e = __builtin_amdgcn_mfma_f32_32x32x16_bf16(afr, bfr, e, 0, 0, 0);
    }
    const int kcol = 32*kb + l31;
    #pragma unroll
    for (int r = 0; r < 16; ++r){
      int c = 32*mb + (r & 3) + 8*(r >> 2) + 4*h;
      ABUF[c*KS + kcol] = f2bf(e[r]);
    }
  }
  __syncthreads();

  // ---- phase 3: extract pre-swizzled A-fragments -> ws ----
  for (int i = tid; i < 640; i += 256){
    int f = i >> 6, ln = i & 63;
    int mb = f / 5, kk = f - 5*mb;
    int c  = 32*mb + (ln & 31);
    int kb2 = 16*kk + 8*(ln >> 5);
    short8v v = lds_load8(&ABUF[c*KS + kb2]);
    *((short8v*)(((unsigned short*)(ws + OFF_AF)) + (size_t)i * 8)) = v;
  }
}

// One block = ONE WAVE = one ray (round-8 structure). The MFMA is split
// along the SAMPLE axis: pass 1 (b0, samples 0..31) holds acc00+acc10
// (32 AGPR) and folds straight into pr0..2; pass 2 (b1) reuses the same
// accumulators into pr3..5. af[10] stays resident (no transient reload —
// r9's mistake); only one b-operand (8 VGPR) live per pass. Target:
// total regs <= 128 -> 4-waves/SIMD bracket (was 152 -> 2/SIMD).
__global__ __launch_bounds__(64, 4)
void neus_render(const float* __restrict__ rays_o, const float* __restrict__ rays_d,
                 const float* __restrict__ inv_s_p, const float* __restrict__ ws,
                 float* __restrict__ out)
{
  __shared__ unsigned short s_aext[64*KS];   // activation rows (bf16), reused per batch
  __shared__ float4 s_wc2[64];
  __shared__ float  s_z[64];
  __shared__ float  s_cdf[64];
  __shared__ float  s_newz[64];
  __shared__ float  s_zall[128];

  const int lane = threadIdx.x;
  const int ray  = blockIdx.x;

  const float4* __restrict__ pW1  = (const float4*)(ws + OFF_W1);
  const float4* __restrict__ pW1E = (const float4*)(ws + OFF_W1E);
  const float4* __restrict__ pW1S = (const float4*)(ws + OFF_W1S);
  const float*  __restrict__ pbc2 = ws + OFF_BC2;
  const float*  __restrict__ pgc  = ws + OFF_GC;
  const float b20 = pbc2[3];

  s_wc2[lane] = ((const float4*)(ws + OFF_WC2))[lane];

  // ---- per-ray setup ----
  float ox = rays_o[ray*3], oy = rays_o[ray*3+1], oz = rays_o[ray*3+2];
  float dx = rays_d[ray*3], dy = rays_d[ray*3+1], dz = rays_d[ray*3+2];
  const float inv_s = expf(10.f * inv_s_p[0]);   // independent load, hoisted
  float tnx = (-1.f-ox)/(dx+1e-15f), tfx = (1.f-ox)/(dx+1e-15f);
  float tny = (-1.f-oy)/(dy+1e-15f), tfy = (1.f-oy)/(dy+1e-15f);
  float tnz = (-1.f-oz)/(dz+1e-15f), tfz = (1.f-oz)/(dz+1e-15f);
  float nearv = fmaxf(fmaxf(fminf(tnx,tfx), fminf(tny,tfy)), fminf(tnz,tfz));
  float farv  = fminf(fminf(fmaxf(tnx,tfx), fmaxf(tny,tfy)), fmaxf(tnz,tfz));
  nearv = fmaxf(nearv, 0.05f);
  const float sd = (farv - nearv) * (1.f/64.f);

  // ---- coarse pass (lane = coarse sample) ----
  {
    float zt = nearv + (farv-nearv) * ((float)lane * (1.f/63.f));
    float px = clampf(ox + dx*zt, -1.f, 1.f);
    float py = clampf(oy + dy*zt, -1.f, 1.f);
    float pz = clampf(oz + dz*zt, -1.f, 1.f);
    float acc0 = b20, acc1 = 0.f;   // 2 chains: halve the serial fma depth
    #pragma unroll 4
    for (int q = 0; q < 32; ++q){
      int j = 2*q;
      float4 wa = pW1[j];
      float4 wb = pW1[j+1];
      float ea = pW1E[j].w;
      float eb = pW1E[j+1].w;
      float ha = fmaxf(fmaf(px, wa.x, fmaf(py, wa.y, fmaf(pz, wa.z, wa.w))), 0.f);
      float hb = fmaxf(fmaf(px, wb.x, fmaf(py, wb.y, fmaf(pz, wb.z, wb.w))), 0.f);
      acc0 = fmaf(ha, ea, acc0);
      acc1 = fmaf(hb, eb, acc1);
    }
    float acc = acc0 + acc1;
    s_z[lane] = zt;
    float s1  = __shfl_down(acc, 1);
    float zt1 = nearv + (farv-nearv) * ((float)(lane+1) * (1.f/63.f));
    float a_c = 0.f, qv = 1.f;
    if (lane < 63){
      float dc   = zt1 - zt;
      float mid  = 0.5f*(acc + s1);
      float cosv = clampf((s1-acc)/(dc+1e-5f), -1000.f, 0.f);
      float est  = cosv*dc*0.5f;
      float pcv  = sigm((mid-est)*64.f);
      float ncv  = sigm((mid+est)*64.f);
      a_c = clampf((pcv-ncv+1e-5f)/(pcv+1e-5f), 0.f, 1.f);
      qv  = 1.f - a_c + 1e-7f;
    }
    float p = qv;
    #pragma unroll
    for (int off = 1; off < 64; off <<= 1){
      float t = __shfl_up(p, off);
      if (lane >= off) p *= t;
    }
    float ec = __shfl_up(p, 1);
    if (lane == 0) ec = 1.f;
    float wvv = (lane < 63) ? (a_c*ec + 1e-5f) : 0.f;
    float tot = wvv;
    #pragma unroll
    for (int off = 32; off > 0; off >>= 1) tot += __shfl_xor(tot, off);
    float cs = wvv;
    #pragma unroll
    for (int off = 1; off < 64; off <<= 1){
      float t = __shfl_up(cs, off);
      if (lane >= off) cs += t;
    }
    if (lane == 0)  s_cdf[0] = 0.f;
    if (lane < 63)  s_cdf[lane+1] = cs / tot;
  }
  __syncthreads();   // 1-wave barrier: memory ordering only

  // ---- sample_pdf (searchsorted right + lerp) ----
  {
    float u = ((float)lane + 0.5f) * (1.f/64.f);
    int lo = 0, hi = 64;
    while (lo < hi){
      int m = (lo+hi) >> 1;
      if (s_cdf[m] <= u) lo = m+1; else hi = m;
    }
    int below = lo - 1;
    int above = lo < 63 ? lo : 63;
    float cb = s_cdf[below], ca = s_cdf[above];
    float bb = s_z[below],   ba = s_z[above];
    float den = ca - cb; if (den < 1e-5f) den = 1.f;
    float tt = (u - cb)/den;
    s_newz[lane] = bb + tt*(ba - bb);
  }
  __syncthreads();

  // A-fragments (weights, pre-swizzled bf16) — loaded ONCE per ray, resident
  const short8v* pAF = (const short8v*)(ws + OFF_AF);
  short8v af[10];
  #pragma unroll
  for (int f = 0; f < 10; ++f) af[f] = pAF[f*64 + lane];

  // ---- parallel merge of two sorted 64-lists (each lane places 2 elems) ----
  {
    float v0 = s_z[lane];
    int lo0 = 0, hi0 = 64;
    while (lo0 < hi0){ int m=(lo0+hi0)>>1; if (s_newz[m] < v0) lo0 = m+1; else hi0 = m; }
    float v1 = s_newz[lane];
    int lo1 = 0, hi1 = 64;
    while (lo1 < hi1){ int m=(lo1+hi1)>>1; if (s_z[m] <= v1) lo1 = m+1; else hi1 = m; }
    s_zall[lane + lo0] = v0;
    s_zall[lane + lo1] = v1;
  }
  __syncthreads();

  // ---- fine pass: 2 batches of 64 samples, one wave, shared aext buffer ----
  unsigned short* arow = &s_aext[(unsigned)lane * KS];
  const unsigned short* aw = s_aext;
  const int scol = lane & 31;
  const int half8 = (lane >> 5) * 8;
  const int halfoff = (lane >> 5) * 4;
  const bool hihalf = (lane >= 32);
  const float gc0 = pgc[0], gc1 = pgc[1], gc2 = pgc[2];
  float rA = 0.f, rB = 0.f, rC = 0.f, rD = 0.f;   // composite accumulators
  float Tc = 1.f;                                  // carried transmittance

  for (int b = 0; b < 2; ++b){
    const int lt2 = 64*b + lane;
    float zc = s_zall[lt2];
    float zn = s_zall[lt2 < 127 ? lt2+1 : 127];
    float delta = (lt2 < 127) ? (zn - zc) : sd;
    float zm    = (lt2 < 127) ? (zc + 0.5f*delta) : zc;
    float px = clampf(ox + dx*zm, -1.f, 1.f);
    float py = clampf(oy + dy*zm, -1.f, 1.f);
    float pz = clampf(oz + dz*zm, -1.f, 1.f);

    // layer-1 + sdf col-0 + FD grad via exact identity:
    //   relu(b+hw)-relu(b-hw) = sgn(w)*(med3(b,-h|w|,h|w|) + h|w|)
    float sa0 = b20, sa1 = 0.f;
    float gxa = gc0, gya = gc1, gza = gc2;
    float gxb = 0.f, gyb = 0.f, gzb = 0.f;
    #pragma unroll 2
    for (int q = 0; q < 16; ++q){
      int j = 4*q;
      float4 w0 = pW1[j],   e0 = pW1E[j],   s0 = pW1S[j];
      float4 w1 = pW1[j+1], e1 = pW1E[j+1], s1v = pW1S[j+1];
      float4 w2 = pW1[j+2], e2 = pW1E[j+2], s2v = pW1S[j+2];
      float4 w3 = pW1[j+3], e3 = pW1E[j+3], s3v = pW1S[j+3];
      float base0 = fmaf(px, w0.x, fmaf(py, w0.y, fmaf(pz, w0.z, w0.w)));
      float base1 = fmaf(px, w1.x, fmaf(py, w1.y, fmaf(pz, w1.z, w1.w)));
      float base2 = fmaf(px, w2.x, fmaf(py, w2.y, fmaf(pz, w2.z, w2.w)));
      float base3 = fmaf(px, w3.x, fmaf(py, w3.y, fmaf(pz, w3.z, w3.w)));
      float hv0 = fmaxf(base0, 0.f), hv1 = fmaxf(base1, 0.f);
      float hv2 = fmaxf(base2, 0.f), hv3 = fmaxf(base3, 0.f);
      sa0 = fmaf(hv0, e0.w, sa0); sa0 = fmaf(hv1, e1.w, sa0);
      sa1 = fmaf(hv2, e2.w, sa1); sa1 = fmaf(hv3, e3.w, sa1);
      gxa = fmaf(__builtin_amdgcn_fmed3f(base0, -e0.x, e0.x), s0.x, gxa);
      gya = fmaf(__builtin_amdgcn_fmed3f(base0, -e0.y, e0.y), s0.y, gya);
      gza = fmaf(__builtin_amdgcn_fmed3f(base0, -e0.z, e0.z), s0.z, gza);
      gxa = fmaf(__builtin_amdgcn_fmed3f(base1, -e1.x, e1.x), s1v.x, gxa);
      gya = fmaf(__builtin_amdgcn_fmed3f(base1, -e1.y, e1.y), s1v.y, gya);
      gza = fmaf(__builtin_amdgcn_fmed3f(base1, -e1.z, e1.z), s1v.z, gza);
      gxb = fmaf(__builtin_amdgcn_fmed3f(base2, -e2.x, e2.x), s2v.x, gxb);
      gyb = fmaf(__builtin_amdgcn_fmed3f(base2, -e2.y, e2.y), s2v.y, gyb);
      gzb = fmaf(__builtin_amdgcn_fmed3f(base2, -e2.z, e2.z), s2v.z, gzb);
      gxb = fmaf(__builtin_amdgcn_fmed3f(base3, -e3.x, e3.x), s3v.x, gxb);
      gyb = fmaf(__builtin_amdgcn_fmed3f(base3, -e3.y, e3.y), s3v.y, gyb);
      gzb = fmaf(__builtin_amdgcn_fmed3f(base3, -e3.z, e3.z), s3v.z, gzb);
      *(unsigned*)&arow[j]   = cvt_pk_bf16(hv0, hv1);
      *(unsigned*)&arow[j+2] = cvt_pk_bf16(hv2, hv3);
    }
    float sdfv = sa0 + sa1;
    float gx = (gxa+gxb)*100.f, gy = (gya+gyb)*100.f, gz = (gza+gzb)*100.f;
    float gn = 1e-5f + sqrtf(gx*gx + gy*gy + gz*gz);
    float nx = gx/gn, ny = gy/gn, nz = gz/gn;

    // ext slots: k=64..72 = [pt,dir,n], k=73 = 1, k=74..79 = 0
    *(unsigned*)&arow[64] = cvt_pk_bf16(px, py);
    *(unsigned*)&arow[66] = cvt_pk_bf16(pz, dx);
    *(unsigned*)&arow[68] = cvt_pk_bf16(dy, dz);
    *(unsigned*)&arow[70] = cvt_pk_bf16(nx, ny);
    *(unsigned*)&arow[72] = cvt_pk_bf16(nz, 1.0f);
    *(unsigned*)&arow[74] = 0u;
    *(unsigned*)&arow[76] = 0u;
    *(unsigned*)&arow[78] = 0u;

    // ---- NeuS alpha + transmittance scan (register-carried across batches) ----
    float tcos = dx*nx + dy*ny + dz*nz;
    float aarg = -100.f * tcos;
    float spv  = (aarg > 0.f) ? (aarg + log1pf(expf(-aarg))) : log1pf(expf(aarg));
    float iter_cos = -(spv * 0.01f);
    float est = iter_cos * delta * 0.5f;
    float pcv = sigm((sdfv - est)*inv_s);
    float ncv = sigm((sdfv + est)*inv_s);
    float alpha = clampf((pcv - ncv + 1e-5f)/(pcv + 1e-5f), 0.f, 1.f);

    float qv = 1.f - alpha + 1e-7f;
    float p = qv;
    #pragma unroll
    for (int off = 1; off < 64; off <<= 1){
      float t = __shfl_up(p, off);
      if (lane >= off) p *= t;
    }
    float excl = __shfl_up(p, 1);
    if (lane == 0) excl = 1.f;
    excl *= Tc;
    float w = alpha * excl;
    Tc *= __shfl(p, 63);

    __syncthreads();   // trivial: fences aext LDS writes before MFMA reads

    // MFMA split along the SAMPLE axis: 2 passes x 2 accumulators (32 AGPR).
    float pr0=0.f,pr1=0.f,pr2=0.f,pr3=0.f,pr4=0.f,pr5=0.f;
    {
      // pass 1: samples 0..31 (b0 operand) -> pr0..2
      f32x16 accA, accB;
      #pragma unroll
      for (int i = 0; i < 16; ++i){ accA[i]=0.f; accB[i]=0.f; }
      #pragma unroll
      for (int kk = 0; kk < 5; ++kk){
        short8v b0 = lds_load8(&aw[ scol * KS + 16*kk + half8]);
        accA = __builtin_amdgcn_mfma_f32_32x32x16_bf16(af[kk],   b0, accA, 0, 0, 0);
        accB = __builtin_amdgcn_mfma_f32_32x32x16_bf16(af[5+kk], b0, accB, 0, 0, 0);
      }
      #pragma unroll
      for (int r = 0; r < 16; ++r){
        int ci = (r & 3) + 8*(r >> 2) + halfoff;
        float4 wA = s_wc2[ci];
        float4 wB = s_wc2[32 + ci];
        float v;
        v = fmaxf(accA[r], 0.f); pr0 = fmaf(v, wA.x, pr0); pr1 = fmaf(v, wA.y, pr1); pr2 = fmaf(v, wA.z, pr2);
        v = fmaxf(accB[r], 0.f); pr0 = fmaf(v, wB.x, pr0); pr1 = fmaf(v, wB.y, pr1); pr2 = fmaf(v, wB.z, pr2);
      }
    }
    {
      // pass 2: samples 32..63 (b1 operand) -> pr3..5
      f32x16 accA, accB;
      #pragma unroll
      for (int i = 0; i < 16; ++i){ accA[i]=0.f; accB[i]=0.f; }
      #pragma unroll
      for (int kk = 0; kk < 5; ++kk){
        short8v b1 = lds_load8(&aw[(32+scol) * KS + 16*kk + half8]);
        accA = __builtin_amdgcn_mfma_f32_32x32x16_bf16(af[kk],   b1, accA, 0, 0, 0);
        accB = __builtin_amdgcn_mfma_f32_32x32x16_bf16(af[5+kk], b1, accB, 0, 0, 0);
      }
      #pragma unroll
      for (int r = 0; r < 16; ++r){
        int ci = (r & 3) + 8*(r >> 2) + halfoff;
        float4 wA = s_wc2[ci];
        float4 wB = s_wc2[32 + ci];
        float v;
        v = fmaxf(accA[r], 0.f); pr3 = fmaf(v, wA.x, pr3); pr4 = fmaf(v, wA.y, pr4); pr5 = fmaf(v, wA.z, pr5);
        v = fmaxf(accB[r], 0.f); pr3 = fmaf(v, wB.x, pr3); pr4 = fmaf(v, wB.y, pr4); pr5 = fmaf(v, wB.z, pr5);
      }
    }

    pr0 += __shfl_xor(pr0, 32); pr1 += __shfl_xor(pr1, 32); pr2 += __shfl_xor(pr2, 32);
    pr3 += __shfl_xor(pr3, 32); pr4 += __shfl_xor(pr4, 32); pr5 += __shfl_xor(pr5, 32);
    float c0 = sigm((hihalf ? pr3 : pr0) + pbc2[0]);
    float c1 = sigm((hihalf ? pr4 : pr1) + pbc2[1]);
    float c2 = sigm((hihalf ? pr5 : pr2) + pbc2[2]);

    rA += w; rB += w*c0; rC += w*c1; rD += w*c2;

    __syncthreads();   // trivial: MFMA reads done before next batch overwrites aext
  }

  // ---- composite (single cross-lane reduce over both batches) ----
  #pragma unroll
  for (int off = 32; off > 0; off >>= 1){
    rA += __shfl_xor(rA, off);
    rB += __shfl_xor(rB, off);
    rC += __shfl_xor(rC, off);
    rD += __shfl_xor(rD, off);
  }
  if (lane == 0){
    float bg = 1.f - rA;
    out[ray*3+0] = rB + bg;
    out[ray*3+1] = rC + bg;
    out[ray*3+2] = rD + bg;
  }
}

extern "C" void kernel_launch(void* const* d_in, const int* in_sizes, int n_in,
                              void* d_out, int out_size, void* d_ws, size_t ws_size,
                              hipStream_t stream)
{
  const float* rays_o = (const float*)d_in[0];
  const float* rays_d = (const float*)d_in[1];
  const float* W1  = (const float*)d_in[2];
  const float* b1  = (const float*)d_in[3];
  const float* W2  = (const float*)d_in[4];
  const float* b2  = (const float*)d_in[5];
  const float* Wc1 = (const float*)d_in[6];
  const float* bc1 = (const float*)d_in[7];
  const float* Wc2 = (const float*)d_in[8];
  const float* bc2 = (const float*)d_in[9];
  const float* inv_s = (const float*)d_in[10];
  float* out = (float*)d_out;
  float* ws  = (float*)d_ws;

  prep_weights<<<1, 256, 0, stream>>>(W1, b1, W2, b2, Wc1, bc1, Wc2, bc2, ws);

  const int R = in_sizes[0] / 3;               // 4096 rays
  dim3 grid(R), block(64);
  neus_render<<<grid, block, 0, stream>>>(rays_o, rays_d, inv_s, ws, out);
}

// Round 12
// 122.649 us; speedup vs baseline: 1.0374x; 1.0140x over previous
//
#include <hip/hip_runtime.h>
#include <hip/hip_bf16.h>
#include <cmath>

#define KS 84   // row stride in ushorts (bank-decorrelated, 8B-aligned rows)

// ---- packed-weight layout in d_ws (float offsets) ----
#define OFF_W1    0      // 64 x float4 {W1[0][j],W1[1][j],W1[2][j],b1[j]}
#define OFF_W1E   256    // 64 x float4 {h|W1x|, h|W1y|, h|W1z|, W2[j][0]}  h=0.005
#define OFF_W1S   512    // 64 x float4 {W2j*sgn(W1x), W2j*sgn(W1y), W2j*sgn(W1z), 0}
#define OFF_WC2   768    // 64 x float4 {Wc2[c][0..2], 0}
#define OFF_BC2   1024   // {bc2[0],bc2[1],bc2[2], b2[0]}
#define OFF_GC    1028   // {sum_j Sx*Hx, sum_j Sy*Hy, sum_j Sz*Hz}  (const half of FD grad)
#define OFF_AF    1032   // 10 frags x 64 lanes x 8 bf16, A-operand-swizzled (16B/lane/frag)

typedef __attribute__((ext_vector_type(4))) short  short4v;
typedef __attribute__((ext_vector_type(8))) short  short8v;
typedef __attribute__((ext_vector_type(16))) float f32x16;

__device__ __forceinline__ float sigm(float x){ return 1.0f/(1.0f + expf(-x)); }
__device__ __forceinline__ float clampf(float x, float lo, float hi){ return fminf(fmaxf(x, lo), hi); }
__device__ __forceinline__ unsigned short f2bf(float x){
  __hip_bfloat16 h = __float2bfloat16(x);
  return *reinterpret_cast<unsigned short*>(&h);
}
// HW packed bf16 convert (RTNE, same rounding as __float2bfloat16):
__device__ __forceinline__ unsigned cvt_pk_bf16(float a, float b){
  unsigned r;
  asm("v_cvt_pk_bf16_f32 %0, %1, %2" : "=v"(r) : "v"(a), "v"(b));
  return r;
}
__device__ __forceinline__ short8v lds_load8(const unsigned short* p){
  short4v lo = *(const short4v*)p;
  short4v hi = *(const short4v*)(p + 4);
  short8v r;
  r[0]=lo[0]; r[1]=lo[1]; r[2]=lo[2]; r[3]=lo[3];
  r[4]=hi[0]; r[5]=hi[1]; r[6]=hi[2]; r[7]=hi[3];
  return r;
}

// Prep (1 block, 256 threads), load-then-compute (unchanged from round 5).
__global__ __launch_bounds__(256)
void prep_weights(const float* __restrict__ W1, const float* __restrict__ b1,
                  const float* __restrict__ W2, const float* __restrict__ b2,
                  const float* __restrict__ Wc1, const float* __restrict__ bc1,
                  const float* __restrict__ Wc2, const float* __restrict__ bc2,
                  float* __restrict__ ws)
{
  __shared__ float LW2[4160];    // (64 x 65)
  __shared__ float LWc1[4672];   // (73 x 64)
  __shared__ float LW1[192];
  __shared__ float Lb1[64];
  __shared__ float Lb2[65];
  __shared__ float Lbc1[64];
  __shared__ float LWc2[192];
  __shared__ float Lbc2[3];
  __shared__ float s_cb[4][64];
  __shared__ unsigned short W2T[64*KS];   // [k][t] = W2[k][1+t] bf16
  __shared__ unsigned short ABUF[64*KS];  // A[c][k] bf16
  const int tid  = threadIdx.x;
  const int lane = tid & 63;
  const int wv   = tid >> 6;
  const int l31  = lane & 31;
  const int h    = lane >> 5;

  // ---- phase 0: coalesced staging ----
  {
    const float4* s4 = (const float4*)W2;
    float4* d4 = (float4*)LW2;
    for (int i = tid; i < 1040; i += 256) d4[i] = s4[i];
    const float4* c4 = (const float4*)Wc1;
    float4* e4 = (float4*)LWc1;
    for (int i = tid; i < 1168; i += 256) e4[i] = c4[i];
  }
  if (tid < 192) LW1[tid]  = W1[tid];
  if (tid < 64)  Lb1[tid]  = b1[tid];
  if (tid < 65)  Lb2[tid]  = b2[tid];
  if (tid < 64)  Lbc1[tid] = bc1[tid];
  if (tid < 192) LWc2[tid] = Wc2[tid];
  if (tid < 3)   Lbc2[tid] = bc2[tid];
  __syncthreads();

  // ---- phase 1 (LDS -> LDS/ws) ----
  for (int i = tid; i < 4096; i += 256){
    int k = i >> 6, t = i & 63;
    W2T[k*KS + t] = f2bf(LW2[k*65 + 1 + t]);
  }
  for (int i = tid; i < 576; i += 256){
    int ii = i >> 6, c = i & 63;
    ABUF[c*KS + 64 + ii] = f2bf(LWc1[ii*64 + c]);
  }
  for (int i = tid; i < 384; i += 256){
    int z = i >> 6, c = i & 63;
    ABUF[c*KS + 74 + z] = 0;
  }
  // cb row partials: thread (q=tid>>6, c=tid&63) sums t in [16q, 16q+16)
  {
    int c = tid & 63, q = tid >> 6;
    float acc = 0.f;
    #pragma unroll
    for (int t = 16*q; t < 16*q + 16; ++t)
      acc = fmaf(Lb2[1+t], LWc1[(9+t)*64 + c], acc);
    s_cb[q][c] = acc;
  }
  // small packs (all of wave 0 -> shfl reduce for gc is wave-uniform)
  if (tid < 64){
    int j = tid;
    float wx = LW1[j], wy = LW1[64+j], wz = LW1[128+j];
    float w2 = LW2[j*65];
    float Hx = 0.005f * fabsf(wx);
    float Hy = 0.005f * fabsf(wy);
    float Hz = 0.005f * fabsf(wz);
    float Sx = (wx < 0.f) ? -w2 : w2;
    float Sy = (wy < 0.f) ? -w2 : w2;
    float Sz = (wz < 0.f) ? -w2 : w2;
    ws[OFF_W1 + 4*j + 0] = wx;
    ws[OFF_W1 + 4*j + 1] = wy;
    ws[OFF_W1 + 4*j + 2] = wz;
    ws[OFF_W1 + 4*j + 3] = Lb1[j];
    ws[OFF_W1E + 4*j + 0] = Hx;
    ws[OFF_W1E + 4*j + 1] = Hy;
    ws[OFF_W1E + 4*j + 2] = Hz;
    ws[OFF_W1E + 4*j + 3] = w2;
    ws[OFF_W1S + 4*j + 0] = Sx;
    ws[OFF_W1S + 4*j + 1] = Sy;
    ws[OFF_W1S + 4*j + 2] = Sz;
    ws[OFF_W1S + 4*j + 3] = 0.f;
    float sx = Sx*Hx, sy = Sy*Hy, sz = Sz*Hz;
    #pragma unroll
    for (int off = 1; off < 64; off <<= 1){
      sx += __shfl_xor(sx, off);
      sy += __shfl_xor(sy, off);
      sz += __shfl_xor(sz, off);
    }
    if (j == 0){
      ws[OFF_GC + 0] = sx;
      ws[OFF_GC + 1] = sy;
      ws[OFF_GC + 2] = sz;
    }
  } else if (tid < 128){
    int j = tid - 64;
    ws[OFF_WC2 + 4*j + 0] = LWc2[j*3+0];
    ws[OFF_WC2 + 4*j + 1] = LWc2[j*3+1];
    ws[OFF_WC2 + 4*j + 2] = LWc2[j*3+2];
    ws[OFF_WC2 + 4*j + 3] = 0.f;
  } else if (tid < 132){
    int j = tid - 128;
    ws[OFF_BC2 + j] = (j < 3) ? Lbc2[j] : Lb2[0];
  }
  __syncthreads();

  // ---- phase 2: cb finalize + per-wave E-tile MFMA ----
  if (tid < 64){
    float acc = Lbc1[tid] + ((s_cb[0][tid] + s_cb[1][tid]) + (s_cb[2][tid] + s_cb[3][tid]));
    ABUF[tid*KS + 73] = f2bf(acc);
  }
  {
    const int mb = wv & 1, kb = wv >> 1;
    f32x16 e;
    #pragma unroll
    for (int i = 0; i < 16; ++i) e[i] = 0.f;
    #pragma unroll
    for (int s = 0; s < 4; ++s){
      short8v afr;
      #pragma unroll
      for (int j = 0; j < 8; ++j)
        afr[j] = (short)f2bf(LWc1[(9 + 16*s + 8*h + j)*64 + 32*mb + l31]);
      short8v bfr = lds_load8(&W2T[(32*kb + l31)*KS + 16*s + 8*h]);
      e = __builtin_amdgcn_mfma_f32_32x32x16_bf16(afr, bfr, e, 0, 0, 0);
    }
    const int kcol = 32*kb + l31;
    #pragma unroll
    for (int r = 0; r < 16; ++r){
      int c = 32*mb + (r & 3) + 8*(r >> 2) + 4*h;
      ABUF[c*KS + kcol] = f2bf(e[r]);
    }
  }
  __syncthreads();

  // ---- phase 3: extract pre-swizzled A-fragments -> ws ----
  for (int i = tid; i < 640; i += 256){
    int f = i >> 6, ln = i & 63;
    int mb = f / 5, kk = f - 5*mb;
    int c  = 32*mb + (ln & 31);
    int kb2 = 16*kk + 8*(ln >> 5);
    short8v v = lds_load8(&ABUF[c*KS + kb2]);
    *((short8v*)(((unsigned short*)(ws + OFF_AF)) + (size_t)i * 8)) = v;
  }
}

// One block = ONE WAVE = one ray. The whole ray pipeline (coarse 64 samples,
// sample_pdf, merge, fine 128 samples as 2 sequential batches over a single
// 64-row aext buffer) runs wave-synchronously: no idle partner wave, all
// __syncthreads are trivial 1-wave barriers (memory-ordering only), LDS
// ~13 KB. Batch-1 transmittance chains through register Tc.
// Best measured configuration (round 8): 44.0 us render / 123.5 us total.
__global__ __launch_bounds__(64, 8)
void neus_render(const float* __restrict__ rays_o, const float* __restrict__ rays_d,
                 const float* __restrict__ inv_s_p, const float* __restrict__ ws,
                 float* __restrict__ out)
{
  __shared__ unsigned short s_aext[64*KS];   // activation rows (bf16), reused per batch
  __shared__ float4 s_wc2[64];
  __shared__ float  s_z[64];
  __shared__ float  s_cdf[64];
  __shared__ float  s_newz[64];
  __shared__ float  s_zall[128];

  const int lane = threadIdx.x;
  const int ray  = blockIdx.x;

  const float4* __restrict__ pW1  = (const float4*)(ws + OFF_W1);
  const float4* __restrict__ pW1E = (const float4*)(ws + OFF_W1E);
  const float4* __restrict__ pW1S = (const float4*)(ws + OFF_W1S);
  const float*  __restrict__ pbc2 = ws + OFF_BC2;
  const float*  __restrict__ pgc  = ws + OFF_GC;
  const float b20 = pbc2[3];

  s_wc2[lane] = ((const float4*)(ws + OFF_WC2))[lane];

  // ---- per-ray setup ----
  float ox = rays_o[ray*3], oy = rays_o[ray*3+1], oz = rays_o[ray*3+2];
  float dx = rays_d[ray*3], dy = rays_d[ray*3+1], dz = rays_d[ray*3+2];
  const float inv_s = expf(10.f * inv_s_p[0]);   // independent load, hoisted
  float tnx = (-1.f-ox)/(dx+1e-15f), tfx = (1.f-ox)/(dx+1e-15f);
  float tny = (-1.f-oy)/(dy+1e-15f), tfy = (1.f-oy)/(dy+1e-15f);
  float tnz = (-1.f-oz)/(dz+1e-15f), tfz = (1.f-oz)/(dz+1e-15f);
  float nearv = fmaxf(fmaxf(fminf(tnx,tfx), fminf(tny,tfy)), fminf(tnz,tfz));
  float farv  = fminf(fminf(fmaxf(tnx,tfx), fmaxf(tny,tfy)), fmaxf(tnz,tfz));
  nearv = fmaxf(nearv, 0.05f);
  const float sd = (farv - nearv) * (1.f/64.f);

  // ---- coarse pass (lane = coarse sample) ----
  {
    float zt = nearv + (farv-nearv) * ((float)lane * (1.f/63.f));
    float px = clampf(ox + dx*zt, -1.f, 1.f);
    float py = clampf(oy + dy*zt, -1.f, 1.f);
    float pz = clampf(oz + dz*zt, -1.f, 1.f);
    float acc0 = b20, acc1 = 0.f;   // 2 chains: halve the serial fma depth
    #pragma unroll 4
    for (int q = 0; q < 32; ++q){
      int j = 2*q;
      float4 wa = pW1[j];
      float4 wb = pW1[j+1];
      float ea = pW1E[j].w;
      float eb = pW1E[j+1].w;
      float ha = fmaxf(fmaf(px, wa.x, fmaf(py, wa.y, fmaf(pz, wa.z, wa.w))), 0.f);
      float hb = fmaxf(fmaf(px, wb.x, fmaf(py, wb.y, fmaf(pz, wb.z, wb.w))), 0.f);
      acc0 = fmaf(ha, ea, acc0);
      acc1 = fmaf(hb, eb, acc1);
    }
    float acc = acc0 + acc1;
    s_z[lane] = zt;
    float s1  = __shfl_down(acc, 1);
    float zt1 = nearv + (farv-nearv) * ((float)(lane+1) * (1.f/63.f));
    float a_c = 0.f, qv = 1.f;
    if (lane < 63){
      float dc   = zt1 - zt;
      float mid  = 0.5f*(acc + s1);
      float cosv = clampf((s1-acc)/(dc+1e-5f), -1000.f, 0.f);
      float est  = cosv*dc*0.5f;
      float pcv  = sigm((mid-est)*64.f);
      float ncv  = sigm((mid+est)*64.f);
      a_c = clampf((pcv-ncv+1e-5f)/(pcv+1e-5f), 0.f, 1.f);
      qv  = 1.f - a_c + 1e-7f;
    }
    float p = qv;
    #pragma unroll
    for (int off = 1; off < 64; off <<= 1){
      float t = __shfl_up(p, off);
      if (lane >= off) p *= t;
    }
    float ec = __shfl_up(p, 1);
    if (lane == 0) ec = 1.f;
    float wvv = (lane < 63) ? (a_c*ec + 1e-5f) : 0.f;
    float tot = wvv;
    #pragma unroll
    for (int off = 32; off > 0; off >>= 1) tot += __shfl_xor(tot, off);
    float cs = wvv;
    #pragma unroll
    for (int off = 1; off < 64; off <<= 1){
      float t = __shfl_up(cs, off);
      if (lane >= off) cs += t;
    }
    if (lane == 0)  s_cdf[0] = 0.f;
    if (lane < 63)  s_cdf[lane+1] = cs / tot;
  }
  __syncthreads();   // 1-wave barrier: memory ordering only

  // ---- sample_pdf (searchsorted right + lerp) ----
  {
    float u = ((float)lane + 0.5f) * (1.f/64.f);
    int lo = 0, hi = 64;
    while (lo < hi){
      int m = (lo+hi) >> 1;
      if (s_cdf[m] <= u) lo = m+1; else hi = m;
    }
    int below = lo - 1;
    int above = lo < 63 ? lo : 63;
    float cb = s_cdf[below], ca = s_cdf[above];
    float bb = s_z[below],   ba = s_z[above];
    float den = ca - cb; if (den < 1e-5f) den = 1.f;
    float tt = (u - cb)/den;
    s_newz[lane] = bb + tt*(ba - bb);
  }
  __syncthreads();

  // A-fragments (weights, pre-swizzled bf16) — loaded ONCE per ray
  const short8v* pAF = (const short8v*)(ws + OFF_AF);
  short8v af[10];
  #pragma unroll
  for (int f = 0; f < 10; ++f) af[f] = pAF[f*64 + lane];

  // ---- parallel merge of two sorted 64-lists (each lane places 2 elems) ----
  {
    float v0 = s_z[lane];
    int lo0 = 0, hi0 = 64;
    while (lo0 < hi0){ int m=(lo0+hi0)>>1; if (s_newz[m] < v0) lo0 = m+1; else hi0 = m; }
    float v1 = s_newz[lane];
    int lo1 = 0, hi1 = 64;
    while (lo1 < hi1){ int m=(lo1+hi1)>>1; if (s_z[m] <= v1) lo1 = m+1; else hi1 = m; }
    s_zall[lane + lo0] = v0;
    s_zall[lane + lo1] = v1;
  }
  __syncthreads();

  // ---- fine pass: 2 batches of 64 samples, one wave, shared aext buffer ----
  unsigned short* arow = &s_aext[(unsigned)lane * KS];
  const unsigned short* aw = s_aext;
  const int scol = lane & 31;
  const int half8 = (lane >> 5) * 8;
  const int halfoff = (lane >> 5) * 4;
  const bool hihalf = (lane >= 32);
  const float gc0 = pgc[0], gc1 = pgc[1], gc2 = pgc[2];
  float rA = 0.f, rB = 0.f, rC = 0.f, rD = 0.f;   // composite accumulators
  float Tc = 1.f;                                  // carried transmittance

  for (int b = 0; b < 2; ++b){
    const int lt2 = 64*b + lane;
    float zc = s_zall[lt2];
    float zn = s_zall[lt2 < 127 ? lt2+1 : 127];
    float delta = (lt2 < 127) ? (zn - zc) : sd;
    float zm    = (lt2 < 127) ? (zc + 0.5f*delta) : zc;
    float px = clampf(ox + dx*zm, -1.f, 1.f);
    float py = clampf(oy + dy*zm, -1.f, 1.f);
    float pz = clampf(oz + dz*zm, -1.f, 1.f);

    // layer-1 + sdf col-0 + FD grad via exact identity:
    //   relu(b+hw)-relu(b-hw) = sgn(w)*(med3(b,-h|w|,h|w|) + h|w|)
    float sa0 = b20, sa1 = 0.f;
    float gxa = gc0, gya = gc1, gza = gc2;
    float gxb = 0.f, gyb = 0.f, gzb = 0.f;
    #pragma unroll 2
    for (int q = 0; q < 16; ++q){
      int j = 4*q;
      float4 w0 = pW1[j],   e0 = pW1E[j],   s0 = pW1S[j];
      float4 w1 = pW1[j+1], e1 = pW1E[j+1], s1v = pW1S[j+1];
      float4 w2 = pW1[j+2], e2 = pW1E[j+2], s2v = pW1S[j+2];
      float4 w3 = pW1[j+3], e3 = pW1E[j+3], s3v = pW1S[j+3];
      float base0 = fmaf(px, w0.x, fmaf(py, w0.y, fmaf(pz, w0.z, w0.w)));
      float base1 = fmaf(px, w1.x, fmaf(py, w1.y, fmaf(pz, w1.z, w1.w)));
      float base2 = fmaf(px, w2.x, fmaf(py, w2.y, fmaf(pz, w2.z, w2.w)));
      float base3 = fmaf(px, w3.x, fmaf(py, w3.y, fmaf(pz, w3.z, w3.w)));
      float hv0 = fmaxf(base0, 0.f), hv1 = fmaxf(base1, 0.f);
      float hv2 = fmaxf(base2, 0.f), hv3 = fmaxf(base3, 0.f);
      sa0 = fmaf(hv0, e0.w, sa0); sa0 = fmaf(hv1, e1.w, sa0);
      sa1 = fmaf(hv2, e2.w, sa1); sa1 = fmaf(hv3, e3.w, sa1);
      gxa = fmaf(__builtin_amdgcn_fmed3f(base0, -e0.x, e0.x), s0.x, gxa);
      gya = fmaf(__builtin_amdgcn_fmed3f(base0, -e0.y, e0.y), s0.y, gya);
      gza = fmaf(__builtin_amdgcn_fmed3f(base0, -e0.z, e0.z), s0.z, gza);
      gxa = fmaf(__builtin_amdgcn_fmed3f(base1, -e1.x, e1.x), s1v.x, gxa);
      gya = fmaf(__builtin_amdgcn_fmed3f(base1, -e1.y, e1.y), s1v.y, gya);
      gza = fmaf(__builtin_amdgcn_fmed3f(base1, -e1.z, e1.z), s1v.z, gza);
      gxb = fmaf(__builtin_amdgcn_fmed3f(base2, -e2.x, e2.x), s2v.x, gxb);
      gyb = fmaf(__builtin_amdgcn_fmed3f(base2, -e2.y, e2.y), s2v.y, gyb);
      gzb = fmaf(__builtin_amdgcn_fmed3f(base2, -e2.z, e2.z), s2v.z, gzb);
      gxb = fmaf(__builtin_amdgcn_fmed3f(base3, -e3.x, e3.x), s3v.x, gxb);
      gyb = fmaf(__builtin_amdgcn_fmed3f(base3, -e3.y, e3.y), s3v.y, gyb);
      gzb = fmaf(__builtin_amdgcn_fmed3f(base3, -e3.z, e3.z), s3v.z, gzb);
      *(unsigned*)&arow[j]   = cvt_pk_bf16(hv0, hv1);
      *(unsigned*)&arow[j+2] = cvt_pk_bf16(hv2, hv3);
    }
    float sdfv = sa0 + sa1;
    float gx = (gxa+gxb)*100.f, gy = (gya+gyb)*100.f, gz = (gza+gzb)*100.f;
    float gn = 1e-5f + sqrtf(gx*gx + gy*gy + gz*gz);
    float nx = gx/gn, ny = gy/gn, nz = gz/gn;

    // ext slots: k=64..72 = [pt,dir,n], k=73 = 1, k=74..79 = 0
    *(unsigned*)&arow[64] = cvt_pk_bf16(px, py);
    *(unsigned*)&arow[66] = cvt_pk_bf16(pz, dx);
    *(unsigned*)&arow[68] = cvt_pk_bf16(dy, dz);
    *(unsigned*)&arow[70] = cvt_pk_bf16(nx, ny);
    *(unsigned*)&arow[72] = cvt_pk_bf16(nz, 1.0f);
    *(unsigned*)&arow[74] = 0u;
    *(unsigned*)&arow[76] = 0u;
    *(unsigned*)&arow[78] = 0u;

    // ---- NeuS alpha + transmittance scan (register-carried across batches) ----
    float tcos = dx*nx + dy*ny + dz*nz;
    float aarg = -100.f * tcos;
    float spv  = (aarg > 0.f) ? (aarg + log1pf(expf(-aarg))) : log1pf(expf(aarg));
    float iter_cos = -(spv * 0.01f);
    float est = iter_cos * delta * 0.5f;
    float pcv = sigm((sdfv - est)*inv_s);
    float ncv = sigm((sdfv + est)*inv_s);
    float alpha = clampf((pcv - ncv + 1e-5f)/(pcv + 1e-5f), 0.f, 1.f);

    float qv = 1.f - alpha + 1e-7f;
    float p = qv;
    #pragma unroll
    for (int off = 1; off < 64; off <<= 1){
      float t = __shfl_up(p, off);
      if (lane >= off) p *= t;
    }
    float excl = __shfl_up(p, 1);
    if (lane == 0) excl = 1.f;
    excl *= Tc;
    float w = alpha * excl;
    Tc *= __shfl(p, 63);

    __syncthreads();   // trivial: fences aext LDS writes before MFMA reads

    // MFMA: C[c][s] = A(64x80) x aext^T(80x64)
    f32x16 acc00, acc01, acc10, acc11;
    #pragma unroll
    for (int i = 0; i < 16; ++i){ acc00[i]=0.f; acc01[i]=0.f; acc10[i]=0.f; acc11[i]=0.f; }
    #pragma unroll
    for (int kk = 0; kk < 5; ++kk){
      int koff = 16*kk + half8;
      short8v b0 = lds_load8(&aw[ scol      * KS + koff]);
      short8v b1 = lds_load8(&aw[(32+scol) * KS + koff]);
      acc00 = __builtin_amdgcn_mfma_f32_32x32x16_bf16(af[kk],   b0, acc00, 0, 0, 0);
      acc10 = __builtin_amdgcn_mfma_f32_32x32x16_bf16(af[5+kk], b0, acc10, 0, 0, 0);
      acc01 = __builtin_amdgcn_mfma_f32_32x32x16_bf16(af[kk],   b1, acc01, 0, 0, 0);
      acc11 = __builtin_amdgcn_mfma_f32_32x32x16_bf16(af[5+kk], b1, acc11, 0, 0, 0);
    }

    // relu -> *Wc2 -> reduce over c: in-lane over regs, cross-half via shfl_xor(32)
    float pr0=0.f,pr1=0.f,pr2=0.f,pr3=0.f,pr4=0.f,pr5=0.f;
    #pragma unroll
    for (int r = 0; r < 16; ++r){
      int ci = (r & 3) + 8*(r >> 2) + halfoff;
      float4 wA = s_wc2[ci];
      float4 wB = s_wc2[32 + ci];
      float v;
      v = fmaxf(acc00[r], 0.f); pr0 = fmaf(v, wA.x, pr0); pr1 = fmaf(v, wA.y, pr1); pr2 = fmaf(v, wA.z, pr2);
      v = fmaxf(acc10[r], 0.f); pr0 = fmaf(v, wB.x, pr0); pr1 = fmaf(v, wB.y, pr1); pr2 = fmaf(v, wB.z, pr2);
      v = fmaxf(acc01[r], 0.f); pr3 = fmaf(v, wA.x, pr3); pr4 = fmaf(v, wA.y, pr4); pr5 = fmaf(v, wA.z, pr5);
      v = fmaxf(acc11[r], 0.f); pr3 = fmaf(v, wB.x, pr3); pr4 = fmaf(v, wB.y, pr4); pr5 = fmaf(v, wB.z, pr5);
    }
    pr0 += __shfl_xor(pr0, 32); pr1 += __shfl_xor(pr1, 32); pr2 += __shfl_xor(pr2, 32);
    pr3 += __shfl_xor(pr3, 32); pr4 += __shfl_xor(pr4, 32); pr5 += __shfl_xor(pr5, 32);
    float c0 = sigm((hihalf ? pr3 : pr0) + pbc2[0]);
    float c1 = sigm((hihalf ? pr4 : pr1) + pbc2[1]);
    float c2 = sigm((hihalf ? pr5 : pr2) + pbc2[2]);

    rA += w; rB += w*c0; rC += w*c1; rD += w*c2;

    __syncthreads();   // trivial: MFMA reads done before next batch overwrites aext
  }

  // ---- composite (single cross-lane reduce over both batches) ----
  #pragma unroll
  for (int off = 32; off > 0; off >>= 1){
    rA += __shfl_xor(rA, off);
    rB += __shfl_xor(rB, off);
    rC += __shfl_xor(rC, off);
    rD += __shfl_xor(rD, off);
  }
  if (lane == 0){
    float bg = 1.f - rA;
    out[ray*3+0] = rB + bg;
    out[ray*3+1] = rC + bg;
    out[ray*3+2] = rD + bg;
  }
}

extern "C" void kernel_launch(void* const* d_in, const int* in_sizes, int n_in,
                              void* d_out, int out_size, void* d_ws, size_t ws_size,
                              hipStream_t stream)
{
  const float* rays_o = (const float*)d_in[0];
  const float* rays_d = (const float*)d_in[1];
  const float* W1  = (const float*)d_in[2];
  const float* b1  = (const float*)d_in[3];
  const float* W2  = (const float*)d_in[4];
  const float* b2  = (const float*)d_in[5];
  const float* Wc1 = (const float*)d_in[6];
  const float* bc1 = (const float*)d_in[7];
  const float* Wc2 = (const float*)d_in[8];
  const float* bc2 = (const float*)d_in[9];
  const float* inv_s = (const float*)d_in[10];
  float* out = (float*)d_out;
  float* ws  = (float*)d_ws;

  prep_weights<<<1, 256, 0, stream>>>(W1, b1, W2, b2, Wc1, bc1, Wc2, bc2, ws);

  const int R = in_sizes[0] / 3;               // 4096 rays
  dim3 grid(R), block(64);
  neus_render<<<grid, block, 0, stream>>>(rays_o, rays_d, inv_s, ws, out);
}